// Round 7
// baseline (1286.296 us; speedup 1.0000x reference)
//
#include <hip/hip_runtime.h>
#include <math.h>

#define BB 8
#define CC 128
#define NN 2048
#define KK 10
#define TWO_CC 256
#define AST 72   // padded LDS stride for candidate tile (breaks 4-way bank conflicts)

typedef double dbl4 __attribute__((ext_vector_type(4)));

__device__ __forceinline__ dbl4 mfma_f64(double a, double b, dbl4 c) {
#if defined(__HIP_DEVICE_COMPILE__)
#  if __has_builtin(__builtin_amdgcn_mfma_f64_16x16x4f64)
    return __builtin_amdgcn_mfma_f64_16x16x4f64(a, b, c, 0, 0, 0);
#  elif __has_builtin(__builtin_amdgcn_mfma_f64_16x16x4_f64)
    return __builtin_amdgcn_mfma_f64_16x16x4_f64(a, b, c, 0, 0, 0);
#  else
    asm volatile("v_mfma_f64_16x16x4_f64 %0, %1, %2, %0"
                 : "+v"(c)
                 : "v"(a), "v"(b));
    return c;
#  endif
#else
    (void)a; (void)b;
    return c;   // host pass: never executed
#endif
}

// exact-ranking comparator: larger key wins; ties -> smaller index (JAX semantics)
__device__ __forceinline__ void insert10(double (&LV)[10], int (&LI)[10], double v, int m) {
    if (v > LV[9] || (v == LV[9] && m < LI[9])) {
        LV[9] = v; LI[9] = m;
#pragma unroll
        for (int q = 9; q >= 1; --q) {
            bool sw = (LV[q] > LV[q - 1]) || (LV[q] == LV[q - 1] && LI[q] < LI[q - 1]);
            double tv = LV[q], tu = LV[q - 1];
            int iv = LI[q], iu = LI[q - 1];
            LV[q]     = sw ? tu : tv;
            LV[q - 1] = sw ? tv : tu;
            LI[q]     = sw ? iu : iv;
            LI[q - 1] = sw ? iv : iu;
        }
    }
}

// ---------------- squared column norms in f64 ----------------
__global__ __launch_bounds__(256) void k_xx(const float* __restrict__ h, double* __restrict__ xx) {
    int t = blockIdx.x * 256 + threadIdx.x;
    if (t >= BB * NN) return;
    int b = t / NN, n = t % NN;
    const float* p = h + (size_t)b * CC * NN + n;
    double s = 0.0;
#pragma unroll
    for (int c = 0; c < CC; ++c) {
        double v = (double)p[(size_t)c * NN];
        s += v * v;
    }
    xx[t] = s;
}

// ---------------- fused KNN: f64 MFMA Gram tiles + per-lane top-10 ----------------
// Layout-agnostic: a probe pair measures, per (lane,reg), which A-side label and
// B-side label the hardware routes to that D slot. We then label candidates/queries
// from the measurement instead of assuming the f64 C/D fragment mapping.
__global__ __launch_bounds__(256) void k_knn(const float* __restrict__ h,
                                             const double* __restrict__ xxg,
                                             int* __restrict__ idxout) {
    __shared__ __align__(16) char smem[45056];
    float* As = (float*)smem;               // [128][AST] k-major candidates
    float* Bq = (float*)(smem + 36864);     // [128][16]  k-major queries
    double* mgV = (double*)smem;            // overlay after m-loop: [16 q][16 lists][10]
    int*    mgI = (int*)(smem + 20480);     // [16][16][10]

    int t = threadIdx.x;
    int lane = t & 63;
    int w = t >> 6;
    int r16 = lane & 15;
    int krow = lane >> 4;
    int b = blockIdx.y;
    int n0 = blockIdx.x * 16;
    const float* hb = h + (size_t)b * CC * NN;
    const double* xxb = xxg + (size_t)b * NN;

    // ---- layout probe: measure D-slot -> (A-label, B-label) routing ----
    dbl4 zz = {0.0, 0.0, 0.0, 0.0};
    dbl4 pa = mfma_f64((double)r16, 0.25, zz);   // A-side: each row constant = its source lane's (lane&15)
    dbl4 pb = mfma_f64(0.25, (double)r16, zz);   // B-side: each col constant = its source lane's (lane&15)
    int Alab[4], Blab[4];
#pragma unroll
    for (int r = 0; r < 4; ++r) {
        Alab[r] = (int)(pa[r] + 0.5);
        Blab[r] = (int)(pb[r] + 0.5);
    }
    // If B-side label varies across regs, the D tile is "transposed" w.r.t. our use:
    // swap MFMA operand roles so each lane owns exactly one query.
    bool swapAB = !(Blab[0] == Blab[1] && Blab[1] == Blab[2] && Blab[2] == Blab[3]);
    int qsub = swapAB ? Alab[0] : Blab[0];       // query sub-index (0..15) owned by this lane
    int cmap[4];
#pragma unroll
    for (int r = 0; r < 4; ++r) cmap[r] = swapAB ? Blab[r] : Alab[r];  // candidate sub-index per reg

    // rank of this lane among the wave's lanes owning the same query (no quad assumption)
    int rank = 0;
    unsigned long long lower = (lane == 63) ? 0x7FFFFFFFFFFFFFFFull : ((1ull << lane) - 1ull);
    for (int v = 0; v < 16; ++v) {
        unsigned long long m = __ballot(qsub == v);
        if (qsub == v) rank = (int)__popcll(m & lower);
    }
    int listid = w * 4 + rank;

    // stage queries Bq[k][n] = h[b][k][n0+n]
#pragma unroll
    for (int i = 0; i < 8; ++i) {
        int G = t + 256 * i;
        int k = G >> 4, n = G & 15;
        Bq[k * 16 + n] = hb[(size_t)k * NN + n0 + n];
    }

    double LV[10]; int LI[10];
#pragma unroll
    for (int q = 0; q < 10; ++q) { LV[q] = -1.0e300; LI[q] = 0x7FFFFFFF; }

    // register prefetch of first candidate tile (64 cols x 128 k)
    float4 pre[8];
#pragma unroll
    for (int i = 0; i < 8; ++i) {
        int G = t + 256 * i;
        int k = G >> 4, mg = G & 15;
        pre[i] = *(const float4*)(hb + (size_t)k * NN + mg * 4);
    }

    for (int mt = 0; mt < 32; ++mt) {
        int m0 = mt * 64;
        __syncthreads();   // previous iter's As reads done (also covers Bq staging on mt=0)
#pragma unroll
        for (int i = 0; i < 8; ++i) {
            int G = t + 256 * i;
            int k = G >> 4, mg = G & 15;
            *(float4*)(As + k * AST + mg * 4) = pre[i];
        }
        __syncthreads();
        if (mt + 1 < 32) {
            int m1 = m0 + 64;
#pragma unroll
            for (int i = 0; i < 8; ++i) {
                int G = t + 256 * i;
                int k = G >> 4, mg = G & 15;
                pre[i] = *(const float4*)(hb + (size_t)k * NN + m1 + mg * 4);
            }
        }

        dbl4 acc = {0.0, 0.0, 0.0, 0.0};
        int am = w * 16 + r16;
        if (!swapAB) {
#pragma unroll 8
            for (int kk = 0; kk < 32; ++kk) {
                double av = (double)As[(kk * 4 + krow) * AST + am];
                double bv = (double)Bq[(kk * 4 + krow) * 16 + r16];
                acc = mfma_f64(av, bv, acc);
            }
        } else {
#pragma unroll 8
            for (int kk = 0; kk < 32; ++kk) {
                double av = (double)Bq[(kk * 4 + krow) * 16 + r16];
                double bv = (double)As[(kk * 4 + krow) * AST + am];
                acc = mfma_f64(av, bv, acc);
            }
        }

        int base_m = m0 + w * 16;
#pragma unroll
        for (int r = 0; r < 4; ++r) {
            int cm = base_m + cmap[r];
            double v = 2.0 * acc[r] - xxb[cm];
            insert10(LV, LI, v, cm);
        }
    }

    // merge: 16 lists per query -> 4 -> 1  (slots indexed by measured qsub)
    __syncthreads();
    int base = (qsub * 16 + listid) * 10;
#pragma unroll
    for (int q = 0; q < 10; ++q) { mgV[base + q] = LV[q]; mgI[base + q] = LI[q]; }
    __syncthreads();
    if (t < 64) {
        int n = t >> 2, p = t & 3;
        double MV[10]; int MI[10];
        int b0 = (n * 16 + p * 4) * 10;
#pragma unroll
        for (int q = 0; q < 10; ++q) { MV[q] = mgV[b0 + q]; MI[q] = mgI[b0 + q]; }
        for (int s = 1; s < 4; ++s) {
            int bs = b0 + s * 10;
#pragma unroll
            for (int q = 0; q < 10; ++q) insert10(MV, MI, mgV[bs + q], mgI[bs + q]);
        }
#pragma unroll
        for (int q = 0; q < 10; ++q) { mgV[b0 + q] = MV[q]; mgI[b0 + q] = MI[q]; }
    }
    __syncthreads();
    if (t < 16) {
        int n = t;
        double MV[10]; int MI[10];
        int b0 = n * 16 * 10;
#pragma unroll
        for (int q = 0; q < 10; ++q) { MV[q] = mgV[b0 + q]; MI[q] = mgI[b0 + q]; }
        for (int s = 1; s < 4; ++s) {
            int bs = b0 + s * 40;
#pragma unroll
            for (int q = 0; q < 10; ++q) insert10(MV, MI, mgV[bs + q], mgI[bs + q]);
        }
        int* op = idxout + ((size_t)b * NN + n0 + n) * KK;
#pragma unroll
        for (int q = 0; q < 10; ++q) op[q] = MI[q];
    }
}

// ---------------- transpose: ht[b][n][c] = h[b][c][n] ----------------
__global__ __launch_bounds__(256) void k_tr(const float* __restrict__ h, float* __restrict__ ht) {
    __shared__ float tile[32][33];
    int b = blockIdx.z, c0 = blockIdx.y * 32, n0 = blockIdx.x * 32;
    int tx = threadIdx.x & 31, tyy = threadIdx.x >> 5;
    const float* hb = h + (size_t)b * CC * NN;
#pragma unroll
    for (int i = 0; i < 4; ++i)
        tile[tyy + i * 8][tx] = hb[(size_t)(c0 + tyy + i * 8) * NN + n0 + tx];
    __syncthreads();
    float* htb = ht + (size_t)b * NN * CC;
#pragma unroll
    for (int i = 0; i < 4; ++i)
        htb[(size_t)(n0 + tyy + i * 8) * CC + c0 + tx] = tile[tx][tyy + i * 8];
}

// ---------------- coalesced neighbor mean from ht ----------------
__global__ __launch_bounds__(256) void k_gather(const float* __restrict__ ht, const int* __restrict__ idx,
                                                float* __restrict__ M) {
    int bn = blockIdx.x * 2 + (threadIdx.x >> 7);
    int c = threadIdx.x & 127;
    int b = bn >> 11;
    const int* ip = idx + (size_t)bn * KK;
    const float* hb = ht + (size_t)b * NN * CC;
    float s = 0.f;
#pragma unroll
    for (int k = 0; k < KK; ++k) s += hb[(size_t)ip[k] * CC + c];
    M[(size_t)bn * CC + c] = s * (1.f / KK);
}

// ---------------- y = Wa*M + (Wb-Wa)*h + bias ----------------
__global__ __launch_bounds__(256) void k_gemm(const float* __restrict__ M, const float* __restrict__ h,
                                              const float* __restrict__ W, const float* __restrict__ bias,
                                              float* __restrict__ y) {
    __shared__ float Ws[64][33];
    __shared__ float Xs[32][65];
    int b = blockIdx.z;
    int o0 = blockIdx.y * 64;
    int n0 = blockIdx.x * 64;
    int tid = threadIdx.x;
    int tx = tid & 15, ty = tid >> 4;
    float acc[4][4] = {};
    const float* Mb = M + (size_t)b * NN * CC;
    const float* hb = h + (size_t)b * CC * NN;

    for (int c0 = 0; c0 < CC; c0 += 32) {
        for (int i = tid; i < 64 * 32; i += 256) {
            int c = i & 31, o = i >> 5;
            Ws[o][c] = W[(size_t)(o0 + o) * TWO_CC + c0 + c];
        }
        for (int i = tid; i < 64 * 32; i += 256) {
            int c = i & 31, nn = i >> 5;
            Xs[c][nn] = Mb[(size_t)(n0 + nn) * CC + c0 + c];
        }
        __syncthreads();
        for (int c = 0; c < 32; ++c) {
            float a[4], bb[4];
#pragma unroll
            for (int q = 0; q < 4; ++q) { a[q] = Ws[ty * 4 + q][c]; bb[q] = Xs[c][tx * 4 + q]; }
#pragma unroll
            for (int i2 = 0; i2 < 4; ++i2)
#pragma unroll
                for (int j = 0; j < 4; ++j) acc[i2][j] += a[i2] * bb[j];
        }
        __syncthreads();
    }
    for (int c0 = 0; c0 < CC; c0 += 32) {
        for (int i = tid; i < 64 * 32; i += 256) {
            int c = i & 31, o = i >> 5;
            const float* wr = W + (size_t)(o0 + o) * TWO_CC;
            Ws[o][c] = wr[CC + c0 + c] - wr[c0 + c];
        }
        for (int i = tid; i < 64 * 32; i += 256) {
            int nn = i & 63, c = i >> 6;
            Xs[c][nn] = hb[(size_t)(c0 + c) * NN + n0 + nn];
        }
        __syncthreads();
        for (int c = 0; c < 32; ++c) {
            float a[4], bb[4];
#pragma unroll
            for (int q = 0; q < 4; ++q) { a[q] = Ws[ty * 4 + q][c]; bb[q] = Xs[c][tx * 4 + q]; }
#pragma unroll
            for (int i2 = 0; i2 < 4; ++i2)
#pragma unroll
                for (int j = 0; j < 4; ++j) acc[i2][j] += a[i2] * bb[j];
        }
        __syncthreads();
    }
#pragma unroll
    for (int i2 = 0; i2 < 4; ++i2) {
        int o = o0 + ty * 4 + i2;
        float bv = bias[o];
#pragma unroll
        for (int j = 0; j < 4; ++j)
            y[((size_t)b * CC + o) * NN + n0 + tx * 4 + j] = acc[i2][j] + bv;
    }
}

// ---------------- per-(b,o) mean/var(ddof=1), relu, optional residual ----------------
__global__ __launch_bounds__(256) void k_norm(const float* __restrict__ y, const float* __restrict__ res,
                                              float* __restrict__ out, int add_res) {
    int bo = blockIdx.x;
    const float* row = y + (size_t)bo * NN;
    float s = 0.f, s2 = 0.f;
    for (int n = threadIdx.x; n < NN; n += 256) {
        float v = row[n];
        s += v;
        s2 += v * v;
    }
#pragma unroll
    for (int off = 32; off > 0; off >>= 1) {
        s += __shfl_down(s, off, 64);
        s2 += __shfl_down(s2, off, 64);
    }
    __shared__ float ss[4], ss2[4];
    int wave = threadIdx.x >> 6, lane = threadIdx.x & 63;
    if (lane == 0) { ss[wave] = s; ss2[wave] = s2; }
    __syncthreads();
    if (threadIdx.x == 0) {
        float S = ss[0] + ss[1] + ss[2] + ss[3];
        float S2 = ss2[0] + ss2[1] + ss2[2] + ss2[3];
        float mean = S * (1.f / NN);
        float var = (S2 - S * mean) * (1.f / (NN - 1));
        ss[0] = mean;
        ss2[0] = rsqrtf(var + 1e-3f);
    }
    __syncthreads();
    float mean = ss[0], inv = ss2[0];
    for (int n = threadIdx.x; n < NN; n += 256) {
        float v = (row[n] - mean) * inv;
        v = fmaxf(v, 0.f);
        if (add_res) v += res[(size_t)bo * NN + n];
        out[(size_t)bo * NN + n] = v;
    }
}

extern "C" void kernel_launch(void* const* d_in, const int* in_sizes, int n_in,
                              void* d_out, int out_size, void* d_ws, size_t ws_size,
                              hipStream_t stream) {
    const float* x  = (const float*)d_in[0];
    const float* W1 = (const float*)d_in[1];
    const float* b1 = (const float*)d_in[2];
    const float* W2 = (const float*)d_in[3];
    const float* b2 = (const float*)d_in[4];
    float* out = (float*)d_out;

    char* wsb = (char*)d_ws;
    double* xx = (double*)wsb;                          // 8*2048 f64
    char* p = wsb + (size_t)BB * NN * 8;
    int* idx = (int*)p;       p += (size_t)BB * NN * KK * 4;
    float* ht = (float*)p;    p += (size_t)BB * NN * CC * 4;
    float* M  = (float*)p;    p += (size_t)BB * NN * CC * 4;
    float* y  = (float*)p;    p += (size_t)BB * CC * NN * 4;
    float* h1 = (float*)p;

    auto layer = [&](const float* hin, const float* Wt, const float* bt, float* hout, int add_res) {
        hipLaunchKernelGGL(k_xx, dim3((BB * NN) / 256), dim3(256), 0, stream, hin, xx);
        hipLaunchKernelGGL(k_tr, dim3(NN / 32, CC / 32, BB), dim3(256), 0, stream, hin, ht);
        hipLaunchKernelGGL(k_knn, dim3(NN / 16, BB), dim3(256), 0, stream, hin, xx, idx);
        hipLaunchKernelGGL(k_gather, dim3(BB * NN / 2), dim3(256), 0, stream, ht, idx, M);
        hipLaunchKernelGGL(k_gemm, dim3(NN / 64, CC / 64, BB), dim3(256), 0, stream, M, hin, Wt, bt, y);
        hipLaunchKernelGGL(k_norm, dim3(BB * CC), dim3(256), 0, stream, y, x, hout, add_res);
    };

    layer(x, W1, b1, h1, 0);
    layer(h1, W2, b2, out, 1);
}